// Round 16
// baseline (214.426 us; speedup 1.0000x reference)
//
#include <hip/hip_runtime.h>

#define NN 24
#define POWER_ITERS 30
#define FISTA_ITERS 200

// Strategy (R8 structure + f16-packed G via v_fma_mix):
//  - 4 lanes/batch, quad DPP exchange (R8: proved best passing, 147us).
//  - G stored as packed-f16 pairs GH (72 u32/lane) -> fits the ~104 arch-VGPR
//    grant => no per-iter v_accvgpr tax (R8's audit: 353 vs 198 instr/iter).
//  - matvec via v_fma_mix_f32: f16 G element (op_sel half) * f32 y + f32 acc.
//    y is NEVER quantized (R15's per-iter RTZ y-jitter is gone).
//  - GL = f16(G - f32(GH)) kept cold (AGPR, touched twice): at iters 50/125,
//    bb += GL*l  re-centers the GH fixed point onto the exact-G fixed point
//    (kills R15's static quantization shift, which accumulates along G's
//    near-null eigendirections). Projection/momentum/accum all f32.
typedef __fp16 h2 __attribute__((ext_vector_type(2)));

// acc += f32(lo16(g)) * y   /   acc += f32(hi16(g)) * y
#define MIXLO(acc, g, y) \
    asm("v_fma_mix_f32 %0, %1, %2, %0 op_sel:[0,0,0] op_sel_hi:[1,0,0]" \
        : "+v"(acc) : "v"(g), "v"(y))
#define MIXHI(acc, g, y) \
    asm("v_fma_mix_f32 %0, %1, %2, %0 op_sel:[1,0,0] op_sel_hi:[1,0,0]" \
        : "+v"(acc) : "v"(g), "v"(y))

template<int CTRL>
__device__ __forceinline__ float dppf(float v) {
    return __int_as_float(__builtin_amdgcn_mov_dpp(
        __float_as_int(v), CTRL, 0xF, 0xF, true));
}
#define BC0(x) dppf<0x00>(x)
#define BC1(x) dppf<0x55>(x)
#define BC2(x) dppf<0xAA>(x)
#define BC3(x) dppf<0xFF>(x)
#define QX1(x) dppf<0xB1>(x)
#define QX2(x) dppf<0x4E>(x)

// Lane q owns cones {2q,2q+1}: rows {2q,2q+1, 8+4q..11+4q}; y slots
// s0=y[2q] s1=y[2q+1] s2..s5=y[8+4q..11+4q]. Column pair p covers cols
// {2p,2p+1}; broadcast sources per pair (R8-verified mapping):
//  p0:(BC0 s0,BC0 s1) p1:(BC1 s0,BC1 s1) p2:(BC2 s0,BC2 s1) p3:(BC3 s0,BC3 s1)
//  p4:(BC0 s2,BC0 s3) p5:(BC0 s4,BC0 s5) p6:(BC1 s2,BC1 s3) p7:(BC1 s4,BC1 s5)
//  p8:(BC2 s2,BC2 s3) p9:(BC2 s4,BC2 s5) p10:(BC3 s2,BC3 s3) p11:(BC3 s4,BC3 s5)
#define PAIR(G, p, elo, ehi) {                                                 \
    const float ylo_ = (elo), yhi_ = (ehi);                                    \
    MIXLO(g0, G##0[p], ylo_); MIXHI(g0, G##0[p], yhi_);                        \
    MIXLO(g1, G##1[p], ylo_); MIXHI(g1, G##1[p], yhi_);                        \
    MIXLO(g2, G##2[p], ylo_); MIXHI(g2, G##2[p], yhi_);                        \
    MIXLO(g3, G##3[p], ylo_); MIXHI(g3, G##3[p], yhi_);                        \
    MIXLO(g4, G##4[p], ylo_); MIXHI(g4, G##4[p], yhi_);                        \
    MIXLO(g5, G##5[p], ylo_); MIXHI(g5, G##5[p], yhi_); }
#define MATVEC_MIX(G, s0, s1, s2, s3, s4, s5) do {                             \
    PAIR(G, 0,  BC0(s0), BC0(s1)) PAIR(G, 1,  BC1(s0), BC1(s1))               \
    PAIR(G, 2,  BC2(s0), BC2(s1)) PAIR(G, 3,  BC3(s0), BC3(s1))               \
    PAIR(G, 4,  BC0(s2), BC0(s3)) PAIR(G, 5,  BC0(s4), BC0(s5))               \
    PAIR(G, 6,  BC1(s2), BC1(s3)) PAIR(G, 7,  BC1(s4), BC1(s5))               \
    PAIR(G, 8,  BC2(s2), BC2(s3)) PAIR(G, 9,  BC2(s4), BC2(s5))               \
    PAIR(G, 10, BC3(s2), BC3(s3)) PAIR(G, 11, BC3(s4), BC3(s5))               \
} while (0)

__global__ __attribute__((amdgpu_waves_per_eu(1, 2))) void __launch_bounds__(256, 1)
qcqp_kernel(const float* __restrict__ P, const float* __restrict__ qv,
            float* __restrict__ out, int Btot) {
    const int tid = blockIdx.x * blockDim.x + threadIdx.x;
    const int b = tid >> 2;
    if (b >= Btot) return;
    const int q = tid & 3;
    const int rt = 2 * q;
    const int rx = 8 + 4 * q;

    const float* __restrict__ Pb = P + (size_t)b * (NN * NN);
    const float* __restrict__ qb = qv + (size_t)b * NN;

    // ---- Phase 1 (f32, R8-identical): 6 rows of G = P^T P, bb = -(P^T q).
    //      (REG=1e-7 dropped: ~3e-8 rel effect.) AGPR tax confined here. ----
    float GR0[NN], GR1[NN], GR2[NN], GR3[NN], GR4[NN], GR5[NN];
#pragma unroll
    for (int j = 0; j < NN; ++j) {
        GR0[j] = 0.f; GR1[j] = 0.f; GR2[j] = 0.f;
        GR3[j] = 0.f; GR4[j] = 0.f; GR5[j] = 0.f;
    }
    float bb0 = 0.f, bb1 = 0.f, bb2 = 0.f, bb3 = 0.f, bb4 = 0.f, bb5 = 0.f;

#pragma unroll 1
    for (int k = 0; k < NN; ++k) {
        const float* rp = Pb + k * NN;
        float row[NN];
#pragma unroll
        for (int m = 0; m < 6; ++m) {
            const float4 r = *reinterpret_cast<const float4*>(rp + 4 * m);
            row[4 * m + 0] = r.x;
            row[4 * m + 1] = r.y;
            row[4 * m + 2] = r.z;
            row[4 * m + 3] = r.w;
        }
        const float2 at = *reinterpret_cast<const float2*>(rp + rt);
        const float4 axv = *reinterpret_cast<const float4*>(rp + rx);
        const float qk = qb[k];
        bb0 = fmaf(-at.x,  qk, bb0);
        bb1 = fmaf(-at.y,  qk, bb1);
        bb2 = fmaf(-axv.x, qk, bb2);
        bb3 = fmaf(-axv.y, qk, bb3);
        bb4 = fmaf(-axv.z, qk, bb4);
        bb5 = fmaf(-axv.w, qk, bb5);
#pragma unroll
        for (int j = 0; j < NN; ++j) {
            GR0[j] = fmaf(at.x,  row[j], GR0[j]);
            GR1[j] = fmaf(at.y,  row[j], GR1[j]);
            GR2[j] = fmaf(axv.x, row[j], GR2[j]);
            GR3[j] = fmaf(axv.y, row[j], GR3[j]);
            GR4[j] = fmaf(axv.z, row[j], GR4[j]);
            GR5[j] = fmaf(axv.w, row[j], GR5[j]);
        }
    }

    // ---- Split G into GH (f16 pairs, hot) + GL (f16 residual, cold) ----
    int GH0[12], GH1[12], GH2[12], GH3[12], GH4[12], GH5[12];
    int GL0[12], GL1[12], GL2[12], GL3[12], GL4[12], GL5[12];
#define SPLIT(GH, GL, GR)                                                      \
    _Pragma("unroll")                                                          \
    for (int p = 0; p < 12; ++p) {                                             \
        const h2 hp = __builtin_amdgcn_cvt_pkrtz(GR[2 * p], GR[2 * p + 1]);    \
        const float l32 = (float)hp[0], h32 = (float)hp[1];                    \
        const h2 lp = __builtin_amdgcn_cvt_pkrtz(GR[2 * p] - l32,              \
                                                 GR[2 * p + 1] - h32);         \
        GH[p] = __builtin_bit_cast(int, hp);                                   \
        GL[p] = __builtin_bit_cast(int, lp);                                   \
    }
    SPLIT(GH0, GL0, GR0) SPLIT(GH1, GL1, GR1) SPLIT(GH2, GL2, GR2)
    SPLIT(GH3, GL3, GR3) SPLIT(GH4, GL4, GR4) SPLIT(GH5, GL5, GR5)
#undef SPLIT

    // ---- Phase 2: power iteration on GH -> step = 1/(L + 1e-12) ----
    float vo0 = 0.20412414523193150818f;  // 1/sqrt(24)
    float vo1 = vo0, vo2 = vo0, vo3 = vo0, vo4 = vo0, vo5 = vo0;

#pragma unroll 1
    for (int it = 0; it < POWER_ITERS; ++it) {
        float g0 = 0.f, g1 = 0.f, g2 = 0.f, g3 = 0.f, g4 = 0.f, g5 = 0.f;
        MATVEC_MIX(GH, vo0, vo1, vo2, vo3, vo4, vo5);
        float n2 = g0 * g0 + g1 * g1 + g2 * g2 + g3 * g3 + g4 * g4 + g5 * g5;
        n2 += QX1(n2);
        n2 += QX2(n2);
        const float inv = __builtin_amdgcn_rsqf(fmaxf(n2, 1e-60f));
        vo0 = g0 * inv; vo1 = g1 * inv; vo2 = g2 * inv;
        vo3 = g3 * inv; vo4 = g4 * inv; vo5 = g5 * inv;
    }
    float step;
    {
        float g0 = 0.f, g1 = 0.f, g2 = 0.f, g3 = 0.f, g4 = 0.f, g5 = 0.f;
        MATVEC_MIX(GH, vo0, vo1, vo2, vo3, vo4, vo5);
        float Lp = vo0 * g0 + vo1 * g1 + vo2 * g2 + vo3 * g3 + vo4 * g4 + vo5 * g5;
        Lp += QX1(Lp);
        Lp += QX2(Lp);
        step = __builtin_amdgcn_rcpf(Lp + 1e-12f);
    }
    const float nstep = -step;

    // ---- Phase 3: FISTA (all state f32) ----
    float yo0 = 0.f, yo1 = 0.f, yo2 = 0.f, yo3 = 0.f, yo4 = 0.f, yo5 = 0.f;
    float lo0 = 0.f, lo1 = 0.f, lo2 = 0.f, lo3 = 0.f, lo4 = 0.f, lo5 = 0.f;
    float tk = 1.f;

#pragma unroll 1
    for (int it = 0; it < FISTA_ITERS; ++it) {
        if (it == 50 || it == 125) {
            // Fixed-point re-centering: bb += GL * l  (one cold GL touch).
            float g0 = 0.f, g1 = 0.f, g2 = 0.f, g3 = 0.f, g4 = 0.f, g5 = 0.f;
            MATVEC_MIX(GL, lo0, lo1, lo2, lo3, lo4, lo5);
            bb0 += g0; bb1 += g1; bb2 += g2;
            bb3 += g3; bb4 += g4; bb5 += g5;
        }
        float g0 = bb0, g1 = bb1, g2 = bb2, g3 = bb3, g4 = bb4, g5 = bb5;
        MATVEC_MIX(GH, yo0, yo1, yo2, yo3, yo4, yo5);
        const float tA  = fmaf(nstep, g0, yo0);
        const float tB  = fmaf(nstep, g1, yo1);
        const float xA1 = fmaf(nstep, g2, yo2);
        const float xA2 = fmaf(nstep, g3, yo3);
        const float xB1 = fmaf(nstep, g4, yo4);
        const float xB2 = fmaf(nstep, g5, yo5);
        const float nxA = __builtin_amdgcn_sqrtf(fmaf(xA1, xA1, xA2 * xA2));
        const float nxB = __builtin_amdgcn_sqrtf(fmaf(xB1, xB1, xB2 * xB2));
        const float alA = 0.5f * (tA + nxA);
        const float alB = 0.5f * (tB + nxB);
        const bool inA = (nxA <= tA), zA = (nxA <= -tA);
        const bool inB = (nxB <= tB), zB = (nxB <= -tB);
        const float lnA0 = inA ? tA : (zA ? 0.f : alA);
        const float lnB0 = inB ? tB : (zB ? 0.f : alB);
        const float scA = inA ? 1.f
                              : (zA ? 0.f : alA * __builtin_amdgcn_rcpf(fmaxf(nxA, 1e-12f)));
        const float scB = inB ? 1.f
                              : (zB ? 0.f : alB * __builtin_amdgcn_rcpf(fmaxf(nxB, 1e-12f)));
        const float lnA1 = xA1 * scA, lnA2 = xA2 * scA;
        const float lnB1 = xB1 * scB, lnB2 = xB2 * scB;
        const float tkn = 0.5f * (1.f + __builtin_amdgcn_sqrtf(fmaf(4.f * tk, tk, 1.f)));
        const float bet = (tk - 1.f) * __builtin_amdgcn_rcpf(tkn);
        tk = tkn;
        yo0 = fmaf(bet, lnA0 - lo0, lnA0); lo0 = lnA0;
        yo1 = fmaf(bet, lnB0 - lo1, lnB0); lo1 = lnB0;
        yo2 = fmaf(bet, lnA1 - lo2, lnA1); lo2 = lnA1;
        yo3 = fmaf(bet, lnA2 - lo3, lnA2); lo3 = lnA2;
        yo4 = fmaf(bet, lnB1 - lo4, lnB1); lo4 = lnB1;
        yo5 = fmaf(bet, lnB2 - lo5, lnB2); lo5 = lnB2;
    }

    // ---- store (disjoint across the quad, covers all 24) ----
    float* ob = out + (size_t)b * NN;
    *reinterpret_cast<float2*>(ob + rt) = make_float2(lo0, lo1);
    *reinterpret_cast<float4*>(ob + rx) = make_float4(lo2, lo3, lo4, lo5);
}

extern "C" void kernel_launch(void* const* d_in, const int* in_sizes, int n_in,
                              void* d_out, int out_size, void* d_ws, size_t ws_size,
                              hipStream_t stream) {
    const float* P = (const float*)d_in[0];
    const float* q = (const float*)d_in[1];
    float* out = (float*)d_out;
    const int Btot = in_sizes[0] / (NN * NN);
    const long long threads = 4LL * Btot;
    const int block = 256;
    const int grid = (int)((threads + block - 1) / block);
    qcqp_kernel<<<grid, block, 0, stream>>>(P, q, out, Btot);
}